// Round 1
// baseline (560.921 us; speedup 1.0000x reference)
//
#include <hip/hip_runtime.h>
#include <hip/hip_bf16.h>

#define F_NODE 128
#define F_EDGE 128
#define MSG_W  (F_NODE + F_EDGE)   // 256
#define OUT_W  (F_NODE + MSG_W)    // 384

// ---------------------------------------------------------------------------
// Kernel 1: count edges per destination node (counts must be pre-zeroed)
// ---------------------------------------------------------------------------
__global__ void count_kernel(const int* __restrict__ row, int* __restrict__ counts, int E) {
    int e = blockIdx.x * blockDim.x + threadIdx.x;
    if (e < E) atomicAdd(&counts[row[e]], 1);
}

// ---------------------------------------------------------------------------
// Kernel 2: single-block exclusive scan of counts -> offsets[0..n], cursor copy
// ---------------------------------------------------------------------------
__global__ __launch_bounds__(1024) void scan_kernel(const int* __restrict__ counts,
                                                    int* __restrict__ offsets,
                                                    int* __restrict__ cursor, int n) {
    __shared__ int s[1024];
    __shared__ int carry_s;
    const int t = threadIdx.x;
    if (t == 0) carry_s = 0;
    __syncthreads();
    for (int base = 0; base < n; base += 1024) {
        int v = (base + t < n) ? counts[base + t] : 0;
        s[t] = v;
        __syncthreads();
        // Hillis-Steele inclusive scan
        for (int off = 1; off < 1024; off <<= 1) {
            int add = (t >= off) ? s[t - off] : 0;
            __syncthreads();
            s[t] += add;
            __syncthreads();
        }
        int incl  = s[t];
        int carry = carry_s;
        __syncthreads();
        if (t == 1023) carry_s = carry + incl;   // inclusive total of this tile
        if (base + t < n) {
            int excl = carry + incl - v;
            offsets[base + t] = excl;
            cursor[base + t]  = excl;
        }
        __syncthreads();
    }
    if (t == 0) offsets[n] = carry_s;
}

// ---------------------------------------------------------------------------
// Kernel 3: bucket edge ids by destination (CSR build)
// ---------------------------------------------------------------------------
__global__ void scatter_kernel(const int* __restrict__ row, int* __restrict__ cursor,
                               int* __restrict__ edge_sorted, int E) {
    int e = blockIdx.x * blockDim.x + threadIdx.x;
    if (e < E) {
        int pos = atomicAdd(&cursor[row[e]], 1);
        edge_sorted[pos] = e;
    }
}

// ---------------------------------------------------------------------------
// Kernel 4: per-node aggregation. One block per node, 256 threads.
// Waves 0-1 (t<128) accumulate gathered x[col]; waves 2-3 accumulate edge_attr.
// ---------------------------------------------------------------------------
#define TILE 64
__global__ __launch_bounds__(256) void aggregate_kernel(
    const float* __restrict__ x, const int* __restrict__ col_idx,
    const float* __restrict__ edge_attr, const int* __restrict__ offsets,
    const int* __restrict__ edge_sorted, float* __restrict__ out, int n_nodes) {

    const int node = blockIdx.x;
    if (node >= n_nodes) return;
    const int t = threadIdx.x;

    const int start = offsets[node];
    const int end   = offsets[node + 1];

    __shared__ int s_e[TILE];
    __shared__ int s_c[TILE];

    float sum = 0.0f;
    for (int base = start; base < end; base += TILE) {
        const int m = min(TILE, end - base);
        if (t < m) {
            int e   = edge_sorted[base + t];
            s_e[t]  = e;
            s_c[t]  = col_idx[e];
        }
        __syncthreads();
        if (t < F_NODE) {
            for (int i = 0; i < m; ++i)
                sum += x[(size_t)s_c[i] * F_NODE + t];
        } else {
            const int tt = t - F_NODE;
            for (int i = 0; i < m; ++i)
                sum += edge_attr[(size_t)s_e[i] * F_EDGE + tt];
        }
        __syncthreads();
    }

    const float cnt  = (float)(end - start);
    const float mean = sum * (1.0f / fmaxf(cnt, 1.0f));

    float* orow = out + (size_t)node * OUT_W;
    orow[F_NODE + t] = mean;                       // cols 128..383
    if (t < F_NODE) orow[t] = x[(size_t)node * F_NODE + t];  // cols 0..127
}

// ---------------------------------------------------------------------------
extern "C" void kernel_launch(void* const* d_in, const int* in_sizes, int n_in,
                              void* d_out, int out_size, void* d_ws, size_t ws_size,
                              hipStream_t stream) {
    const float* x          = (const float*)d_in[0];
    const int*   edge_index = (const int*)d_in[1];
    const float* edge_attr  = (const float*)d_in[2];
    // d_in[3] = u (unused), d_in[4] = batch (unused)

    const int n_nodes = in_sizes[0] / F_NODE;      // 10000
    const int E       = in_sizes[1] / 2;           // 640000
    const int* row = edge_index;                   // destinations
    const int* col = edge_index + E;               // sources

    // workspace layout (ints)
    int* counts      = (int*)d_ws;                 // n_nodes
    int* offsets     = counts + n_nodes;           // n_nodes + 1
    int* cursor      = offsets + n_nodes + 1;      // n_nodes
    int* edge_sorted = cursor + n_nodes;           // E

    float* out = (float*)d_out;

    hipMemsetAsync(counts, 0, (size_t)n_nodes * sizeof(int), stream);

    const int TB = 256;
    count_kernel<<<(E + TB - 1) / TB, TB, 0, stream>>>(row, counts, E);
    scan_kernel<<<1, 1024, 0, stream>>>(counts, offsets, cursor, n_nodes);
    scatter_kernel<<<(E + TB - 1) / TB, TB, 0, stream>>>(row, cursor, edge_sorted, E);
    aggregate_kernel<<<n_nodes, 256, 0, stream>>>(x, col, edge_attr, offsets,
                                                  edge_sorted, out, n_nodes);
}